// Round 1
// baseline (131.503 us; speedup 1.0000x reference)
//
#include <hip/hip_runtime.h>

#define TGT 256
#define SRC 256
#define LDIM 256
#define DM 512
#define BATCH 8

#define C2LOG2E 2.8853902f   // 2*log2(e): tanh(x) = 1 - 2/(1+exp2(x*C2LOG2E))
#define LOG2E 1.4426950f
#define LN2 0.6931472f
#define LOGEPS -18.420681f   // log(1e-8)

#if __has_builtin(__builtin_amdgcn_exp2f)
#define EXP2F(x) __builtin_amdgcn_exp2f(x)
#else
#define EXP2F(x) exp2f(x)
#endif
#if __has_builtin(__builtin_amdgcn_rcpf)
#define RCPF(x) __builtin_amdgcn_rcpf(x)
#else
#define RCPF(x) (1.0f / (x))
#endif
#if __has_builtin(__builtin_amdgcn_logf)
#define LOG2F_(x) __builtin_amdgcn_logf(x)
#else
#define LOG2F_(x) __log2f(x)
#endif

// ---------------------------------------------------------------------------
// GEMM: rows 0..2047 -> dt = C2LOG2E * (dec @ W1), rows 2048..4095 -> et = C2LOG2E * (enc @ W2)
// 64x64 tile, BK=16, 256 threads, 4x4 microtile.
// ---------------------------------------------------------------------------
__global__ __launch_bounds__(256) void gemm_k(
    const float* __restrict__ dec, const float* __restrict__ enc,
    const float* __restrict__ W1, const float* __restrict__ W2,
    float* __restrict__ dt, float* __restrict__ et)
{
    __shared__ __align__(16) float As[16][68];  // [k][m], padded
    __shared__ __align__(16) float Bs[16][68];  // [k][n], padded

    const int tid = threadIdx.x;
    const int m0 = blockIdx.y * 64;
    const int n0 = blockIdx.x * 64;
    const bool is_dec = (m0 < 2048);
    const float* __restrict__ X = is_dec ? dec : enc;
    const float* __restrict__ W = is_dec ? W1 : W2;
    float* __restrict__ Cdst = is_dec ? dt : et;
    const int xrow0 = is_dec ? m0 : (m0 - 2048);

    const int am = tid >> 2;          // 0..63 : A row within tile
    const int ak = (tid & 3) << 2;    // 0,4,8,12 : A k-quad
    const int bk = tid >> 4;          // 0..15 : B k-row
    const int bn = (tid & 15) << 2;   // 0..60 : B col-quad
    const int ty4 = (tid >> 4) << 2;  // 0..60 : compute row base
    const int tx4 = (tid & 15) << 2;  // 0..60 : compute col base

    float c[4][4] = {};

    for (int k0 = 0; k0 < DM; k0 += 16) {
        const float4 a4 = *(const float4*)(X + (size_t)(xrow0 + am) * DM + k0 + ak);
        As[ak + 0][am] = a4.x;
        As[ak + 1][am] = a4.y;
        As[ak + 2][am] = a4.z;
        As[ak + 3][am] = a4.w;
        const float4 b4 = *(const float4*)(W + (size_t)(k0 + bk) * LDIM + n0 + bn);
        *(float4*)&Bs[bk][bn] = b4;
        __syncthreads();

        #pragma unroll
        for (int kk = 0; kk < 16; ++kk) {
            const float4 av4 = *(const float4*)&As[kk][ty4];
            const float4 bv4 = *(const float4*)&Bs[kk][tx4];
            const float a[4] = {av4.x, av4.y, av4.z, av4.w};
            const float b[4] = {bv4.x, bv4.y, bv4.z, bv4.w};
            #pragma unroll
            for (int i = 0; i < 4; ++i)
                #pragma unroll
                for (int j = 0; j < 4; ++j)
                    c[i][j] = fmaf(a[i], b[j], c[i][j]);
        }
        __syncthreads();
    }

    #pragma unroll
    for (int i = 0; i < 4; ++i) {
        float4 o;
        o.x = c[i][0] * C2LOG2E;
        o.y = c[i][1] * C2LOG2E;
        o.z = c[i][2] * C2LOG2E;
        o.w = c[i][3] * C2LOG2E;
        *(float4*)(Cdst + (size_t)(xrow0 + ty4 + i) * LDIM + n0 + tx4) = o;
    }
}

// ---------------------------------------------------------------------------
// Scores: block = (b, 4 consecutive t). thread = s (256 threads).
// score_shifted[t][s] = sum_l -2*vt[l] / (1 + exp2(dt2[t,l] + et2[s,l]))
// (the constant sum_l vt[l] cancels in log_softmax). Then mask, log_softmax
// over s, write out[b, s, t] (t contiguous per thread -> float4 store).
// ---------------------------------------------------------------------------
__global__ __launch_bounds__(256) void scores_k(
    const float* __restrict__ dt, const float* __restrict__ et,
    const int* __restrict__ lens, const float* __restrict__ vt,
    float* __restrict__ out)
{
    __shared__ __align__(16) float dtr[LDIM][4];  // [l][i] : 4 t-rows, transposed
    __shared__ float vt2s[LDIM];
    __shared__ float4 wred[4];

    const int s = threadIdx.x;
    const int b = blockIdx.y;
    const int t0 = blockIdx.x * 4;

    #pragma unroll
    for (int i = 0; i < 4; ++i)
        dtr[s][i] = dt[(size_t)(b * TGT + t0 + i) * LDIM + s];
    vt2s[s] = -2.0f * vt[s];
    __syncthreads();

    const int len_b = lens[b];
    float4 acc = {0.f, 0.f, 0.f, 0.f};
    const float4* __restrict__ erow = (const float4*)(et + (size_t)(b * SRC + s) * LDIM);

    for (int l0 = 0; l0 < LDIM; l0 += 4) {
        const float4 e4 = erow[l0 >> 2];
        const float ee[4] = {e4.x, e4.y, e4.z, e4.w};
        #pragma unroll
        for (int j = 0; j < 4; ++j) {
            const int l = l0 + j;
            const float v2 = vt2s[l];
            const float4 d4 = *(const float4*)&dtr[l][0];
            acc.x = fmaf(v2, RCPF(1.0f + EXP2F(d4.x + ee[j])), acc.x);
            acc.y = fmaf(v2, RCPF(1.0f + EXP2F(d4.y + ee[j])), acc.y);
            acc.z = fmaf(v2, RCPF(1.0f + EXP2F(d4.z + ee[j])), acc.z);
            acc.w = fmaf(v2, RCPF(1.0f + EXP2F(d4.w + ee[j])), acc.w);
        }
    }

    // mask: s >= len_b gets +log(1e-8); unmasked gets +log(1+1e-8) == 0 in f32
    const float madd = (s < len_b) ? 0.0f : LOGEPS;
    acc.x += madd; acc.y += madd; acc.z += madd; acc.w += madd;

    const int wid = s >> 6, lane = s & 63;

    // ---- block max over s (per t-component) ----
    float4 r = acc;
    #pragma unroll
    for (int off = 32; off > 0; off >>= 1) {
        r.x = fmaxf(r.x, __shfl_down(r.x, off));
        r.y = fmaxf(r.y, __shfl_down(r.y, off));
        r.z = fmaxf(r.z, __shfl_down(r.z, off));
        r.w = fmaxf(r.w, __shfl_down(r.w, off));
    }
    if (lane == 0) wred[wid] = r;
    __syncthreads();
    float4 mx = wred[0];
    #pragma unroll
    for (int w = 1; w < 4; ++w) {
        mx.x = fmaxf(mx.x, wred[w].x);
        mx.y = fmaxf(mx.y, wred[w].y);
        mx.z = fmaxf(mx.z, wred[w].z);
        mx.w = fmaxf(mx.w, wred[w].w);
    }
    __syncthreads();

    // ---- block sum of exp(acc - mx) ----
    float4 ex;
    ex.x = EXP2F((acc.x - mx.x) * LOG2E);
    ex.y = EXP2F((acc.y - mx.y) * LOG2E);
    ex.z = EXP2F((acc.z - mx.z) * LOG2E);
    ex.w = EXP2F((acc.w - mx.w) * LOG2E);
    float4 sr = ex;
    #pragma unroll
    for (int off = 32; off > 0; off >>= 1) {
        sr.x += __shfl_down(sr.x, off);
        sr.y += __shfl_down(sr.y, off);
        sr.z += __shfl_down(sr.z, off);
        sr.w += __shfl_down(sr.w, off);
    }
    if (lane == 0) wred[wid] = sr;
    __syncthreads();
    float4 sm = wred[0];
    #pragma unroll
    for (int w = 1; w < 4; ++w) {
        sm.x += wred[w].x; sm.y += wred[w].y; sm.z += wred[w].z; sm.w += wred[w].w;
    }

    float4 o;
    o.x = acc.x - (mx.x + LOG2F_(sm.x) * LN2);
    o.y = acc.y - (mx.y + LOG2F_(sm.y) * LN2);
    o.z = acc.z - (mx.z + LOG2F_(sm.z) * LN2);
    o.w = acc.w - (mx.w + LOG2F_(sm.w) * LN2);
    *(float4*)(out + (size_t)(b * SRC + s) * TGT + t0) = o;
}

extern "C" void kernel_launch(void* const* d_in, const int* in_sizes, int n_in,
                              void* d_out, int out_size, void* d_ws, size_t ws_size,
                              hipStream_t stream) {
    const float* dec = (const float*)d_in[0];
    const float* enc = (const float*)d_in[1];
    const int* lens  = (const int*)d_in[2];
    const float* W1  = (const float*)d_in[3];
    const float* W2  = (const float*)d_in[4];
    const float* vt  = (const float*)d_in[5];
    float* out = (float*)d_out;

    float* dt = (float*)d_ws;                    // 2048*256 f32 (scaled by 2*log2e)
    float* et = dt + (size_t)2048 * 256;         // 2048*256 f32 (scaled by 2*log2e)

    gemm_k<<<dim3(LDIM / 64, 4096 / 64), 256, 0, stream>>>(dec, enc, W1, W2, dt, et);
    scores_k<<<dim3(TGT / 4, BATCH), 256, 0, stream>>>(dt, et, lens, vt, out);
}

// Round 2
// 98.400 us; speedup vs baseline: 1.3364x; 1.3364x over previous
//
#include <hip/hip_runtime.h>
#include <hip/hip_bf16.h>

#define TGT 256
#define SRC 256
#define LDIM 256
#define DM 512
#define BATCH 8

#define C2LOG2E 2.8853902f   // 2*log2(e): tanh(x) = 1 - 2/(1+exp2(x*C2LOG2E))
#define LOG2E 1.4426950f
#define LN2 0.6931472f
#define LOGEPS -18.420681f   // log(1e-8)

#if __has_builtin(__builtin_amdgcn_exp2f)
#define EXP2F(x) __builtin_amdgcn_exp2f(x)
#else
#define EXP2F(x) exp2f(x)
#endif
#if __has_builtin(__builtin_amdgcn_rcpf)
#define RCPF(x) __builtin_amdgcn_rcpf(x)
#else
#define RCPF(x) (1.0f / (x))
#endif
#if __has_builtin(__builtin_amdgcn_logf)
#define LOG2F_(x) __builtin_amdgcn_logf(x)
#else
#define LOG2F_(x) __log2f(x)
#endif

typedef short bf16x8 __attribute__((ext_vector_type(8)));
typedef float f32x4 __attribute__((ext_vector_type(4)));

__device__ __forceinline__ unsigned int f2b_pk(float lo, float hi) {
    // pack two f32 -> two bf16 (RNE)
    union { float f; unsigned int u; } a, b;
    a.f = lo; b.f = hi;
    unsigned int ra = (a.u + 0x7fffu + ((a.u >> 16) & 1u)) >> 16;
    unsigned int rb = (b.u + 0x7fffu + ((b.u >> 16) & 1u)) >> 16;
    return (ra & 0xffffu) | (rb << 16);
}

// ---------------------------------------------------------------------------
// W transpose+convert: Wt[mat][n][k] bf16 from W[mat][k][n] f32
// ---------------------------------------------------------------------------
__global__ __launch_bounds__(256) void wtrans_k(
    const float* __restrict__ W1, const float* __restrict__ W2,
    unsigned short* __restrict__ Wt)
{
    __shared__ float tile[32][33];
    const int mat = blockIdx.z;
    const float* __restrict__ W = mat ? W2 : W1;
    unsigned short* __restrict__ dst = Wt + (size_t)mat * LDIM * DM;
    const int k0 = blockIdx.x * 32, n0 = blockIdx.y * 32;
    const int tx = threadIdx.x & 31, ty = threadIdx.x >> 5;  // 32 x 8
    #pragma unroll
    for (int i = 0; i < 32; i += 8)
        tile[ty + i][tx] = W[(size_t)(k0 + ty + i) * LDIM + n0 + tx];
    __syncthreads();
    #pragma unroll
    for (int i = 0; i < 32; i += 8) {
        union { float f; unsigned int u; } v; v.f = tile[tx][ty + i];
        dst[(size_t)(n0 + ty + i) * DM + k0 + tx] =
            (unsigned short)((v.u + 0x7fffu + ((v.u >> 16) & 1u)) >> 16);
    }
}

// ---------------------------------------------------------------------------
// MFMA GEMM: E[m][l] = exp2(C2LOG2E * (X[m] . W[:,l])), m in [0,4096)
// rows 0..2047 from dec (W1), rows 2048..4095 from enc (W2).
// 64x64 tile, BK=64, 256 threads (4 waves), 16x16x32 bf16 MFMA.
// A converted f32->bf16 on the fly; B staged from pre-transposed Wt (bf16).
// ---------------------------------------------------------------------------
#define APITCH 72  // bf16 elems per LDS row (64 + 8 pad, keeps 16B align)

__global__ __launch_bounds__(256) void gemm_k(
    const float* __restrict__ dec, const float* __restrict__ enc,
    const unsigned short* __restrict__ Wt, float* __restrict__ E)
{
    __shared__ unsigned short As[64 * APITCH];  // [row m][k]
    __shared__ unsigned short Bs[64 * APITCH];  // [row n][k]

    const int tid = threadIdx.x;
    const int m0 = blockIdx.y * 64;
    const int n0 = blockIdx.x * 64;
    const bool is_dec = (m0 < 2048);
    const float* __restrict__ X = is_dec ? dec : enc;
    const unsigned short* __restrict__ Wm = Wt + (is_dec ? 0 : (size_t)LDIM * DM);
    const int xr0 = is_dec ? m0 : m0 - 2048;

    // staging: thread covers row tid>>2, k-segment (tid&3)*16
    const int arow = tid >> 2;
    const int aseg = (tid & 3) << 4;   // 0,16,32,48 (elements along K)
    const float* __restrict__ aptr = X + (size_t)(xr0 + arow) * DM + aseg;
    const unsigned short* __restrict__ bptr = Wm + (size_t)(n0 + arow) * DM + aseg;

    const int wave = tid >> 6;
    const int lane = tid & 63;
    const int l15 = lane & 15;
    const int quad = lane >> 4;

    f32x4 acc[4] = {};
    float4 a0, a1, a2, a3;
    uint4 bb0, bb1;

    // prefetch iter 0
    a0 = *(const float4*)(aptr + 0);
    a1 = *(const float4*)(aptr + 4);
    a2 = *(const float4*)(aptr + 8);
    a3 = *(const float4*)(aptr + 12);
    bb0 = *(const uint4*)(bptr + 0);
    bb1 = *(const uint4*)(bptr + 8);

    for (int it = 0; it < DM / 64; ++it) {
        if (it) __syncthreads();
        uint4 wa0, wa1;
        wa0.x = f2b_pk(a0.x, a0.y); wa0.y = f2b_pk(a0.z, a0.w);
        wa0.z = f2b_pk(a1.x, a1.y); wa0.w = f2b_pk(a1.z, a1.w);
        wa1.x = f2b_pk(a2.x, a2.y); wa1.y = f2b_pk(a2.z, a2.w);
        wa1.z = f2b_pk(a3.x, a3.y); wa1.w = f2b_pk(a3.z, a3.w);
        *(uint4*)&As[arow * APITCH + aseg]     = wa0;
        *(uint4*)&As[arow * APITCH + aseg + 8] = wa1;
        *(uint4*)&Bs[arow * APITCH + aseg]     = bb0;
        *(uint4*)&Bs[arow * APITCH + aseg + 8] = bb1;
        __syncthreads();
        if (it < DM / 64 - 1) {
            const int ko = (it + 1) * 64;
            a0 = *(const float4*)(aptr + ko + 0);
            a1 = *(const float4*)(aptr + ko + 4);
            a2 = *(const float4*)(aptr + ko + 8);
            a3 = *(const float4*)(aptr + ko + 12);
            bb0 = *(const uint4*)(bptr + ko + 0);
            bb1 = *(const uint4*)(bptr + ko + 8);
        }
        #pragma unroll
        for (int kb = 0; kb < 64; kb += 32) {
            const bf16x8 af = *(const bf16x8*)&As[(wave * 16 + l15) * APITCH + kb + quad * 8];
            #pragma unroll
            for (int c = 0; c < 4; ++c) {
                const bf16x8 bf = *(const bf16x8*)&Bs[(c * 16 + l15) * APITCH + kb + quad * 8];
                acc[c] = __builtin_amdgcn_mfma_f32_16x16x32_bf16(af, bf, acc[c], 0, 0, 0);
            }
        }
    }

    // epilogue: E = exp2(C2LOG2E * dot). C/D layout: col=lane&15, row=quad*4+reg
    const int orow = m0 + wave * 16 + quad * 4;
    const int ocol = n0 + l15;
    #pragma unroll
    for (int c = 0; c < 4; ++c)
        #pragma unroll
        for (int r = 0; r < 4; ++r)
            E[(size_t)(orow + r) * LDIM + ocol + c * 16] = EXP2F(acc[c][r] * C2LOG2E);
}

// ---------------------------------------------------------------------------
// Scores: block = (b, 4 consecutive t). thread = s.
// score_shifted[t][s] = sum_l vt2[l] / (1 + Ed[t,l]*Ee[s,l]),  vt2 = -2*vt
// (constant sum_l vt[l] cancels in log_softmax). Mask, log_softmax over s,
// write out[b, s, t].
// ---------------------------------------------------------------------------
__global__ __launch_bounds__(256) void scores_k(
    const float* __restrict__ E, const int* __restrict__ lens,
    const float* __restrict__ vt, float* __restrict__ out)
{
    __shared__ __align__(16) float dtr[LDIM][4];  // [l][i]: 4 t-rows, transposed
    __shared__ __align__(16) float vt2s[LDIM];
    __shared__ float4 wred[4];

    const int s = threadIdx.x;
    const int b = blockIdx.y;
    const int t0 = blockIdx.x * 4;
    const float* __restrict__ Ed = E;                        // row = b*TGT + t
    const float* __restrict__ Ee = E + (size_t)2048 * LDIM;  // row = b*SRC + s

    #pragma unroll
    for (int i = 0; i < 4; ++i)
        dtr[s][i] = Ed[(size_t)(b * TGT + t0 + i) * LDIM + s];
    vt2s[s] = -2.0f * vt[s];
    __syncthreads();

    const int len_b = lens[b];
    float4 acc = {0.f, 0.f, 0.f, 0.f};
    const float4* __restrict__ erow = (const float4*)(Ee + (size_t)(b * SRC + s) * LDIM);

    for (int l0 = 0; l0 < LDIM; l0 += 4) {
        const float4 e4 = erow[l0 >> 2];
        const float4 v4 = *(const float4*)&vt2s[l0];
        const float ee[4] = {e4.x, e4.y, e4.z, e4.w};
        const float vv[4] = {v4.x, v4.y, v4.z, v4.w};
        #pragma unroll
        for (int j = 0; j < 4; ++j) {
            const float4 d4 = *(const float4*)&dtr[l0 + j][0];
            acc.x = fmaf(vv[j], RCPF(1.0f + d4.x * ee[j]), acc.x);
            acc.y = fmaf(vv[j], RCPF(1.0f + d4.y * ee[j]), acc.y);
            acc.z = fmaf(vv[j], RCPF(1.0f + d4.z * ee[j]), acc.z);
            acc.w = fmaf(vv[j], RCPF(1.0f + d4.w * ee[j]), acc.w);
        }
    }

    const float madd = (s < len_b) ? 0.0f : LOGEPS;
    acc.x += madd; acc.y += madd; acc.z += madd; acc.w += madd;

    const int wid = s >> 6, lane = s & 63;

    float4 r = acc;
    #pragma unroll
    for (int off = 32; off > 0; off >>= 1) {
        r.x = fmaxf(r.x, __shfl_down(r.x, off));
        r.y = fmaxf(r.y, __shfl_down(r.y, off));
        r.z = fmaxf(r.z, __shfl_down(r.z, off));
        r.w = fmaxf(r.w, __shfl_down(r.w, off));
    }
    if (lane == 0) wred[wid] = r;
    __syncthreads();
    float4 mx = wred[0];
    #pragma unroll
    for (int w = 1; w < 4; ++w) {
        mx.x = fmaxf(mx.x, wred[w].x);
        mx.y = fmaxf(mx.y, wred[w].y);
        mx.z = fmaxf(mx.z, wred[w].z);
        mx.w = fmaxf(mx.w, wred[w].w);
    }
    __syncthreads();

    float4 ex;
    ex.x = EXP2F((acc.x - mx.x) * LOG2E);
    ex.y = EXP2F((acc.y - mx.y) * LOG2E);
    ex.z = EXP2F((acc.z - mx.z) * LOG2E);
    ex.w = EXP2F((acc.w - mx.w) * LOG2E);
    float4 sr = ex;
    #pragma unroll
    for (int off = 32; off > 0; off >>= 1) {
        sr.x += __shfl_down(sr.x, off);
        sr.y += __shfl_down(sr.y, off);
        sr.z += __shfl_down(sr.z, off);
        sr.w += __shfl_down(sr.w, off);
    }
    if (lane == 0) wred[wid] = sr;
    __syncthreads();
    float4 sm = wred[0];
    #pragma unroll
    for (int w = 1; w < 4; ++w) {
        sm.x += wred[w].x; sm.y += wred[w].y; sm.z += wred[w].z; sm.w += wred[w].w;
    }

    float4 o;
    o.x = acc.x - (mx.x + LOG2F_(sm.x) * LN2);
    o.y = acc.y - (mx.y + LOG2F_(sm.y) * LN2);
    o.z = acc.z - (mx.z + LOG2F_(sm.z) * LN2);
    o.w = acc.w - (mx.w + LOG2F_(sm.w) * LN2);
    *(float4*)(out + (size_t)(b * SRC + s) * TGT + t0) = o;
}

extern "C" void kernel_launch(void* const* d_in, const int* in_sizes, int n_in,
                              void* d_out, int out_size, void* d_ws, size_t ws_size,
                              hipStream_t stream) {
    const float* dec = (const float*)d_in[0];
    const float* enc = (const float*)d_in[1];
    const int* lens  = (const int*)d_in[2];
    const float* W1  = (const float*)d_in[3];
    const float* W2  = (const float*)d_in[4];
    const float* vt  = (const float*)d_in[5];
    float* out = (float*)d_out;

    unsigned short* Wt = (unsigned short*)d_ws;            // 2*256*512 bf16 = 512 KB
    float* E = (float*)((char*)d_ws + (size_t)2 * LDIM * DM * sizeof(unsigned short));
                                                           // 4096*256 f32 = 4 MB

    wtrans_k<<<dim3(16, 8, 2), 256, 0, stream>>>(W1, W2, Wt);
    gemm_k<<<dim3(LDIM / 64, 4096 / 64), 256, 0, stream>>>(dec, enc, Wt, E);
    scores_k<<<dim3(TGT / 4, BATCH), 256, 0, stream>>>(E, lens, vt, out);
}

// Round 3
// 98.121 us; speedup vs baseline: 1.3402x; 1.0028x over previous
//
#include <hip/hip_runtime.h>
#include <hip/hip_bf16.h>

#define TGT 256
#define SRC 256
#define LDIM 256
#define DM 512
#define BATCH 8

#define C2LOG2E 2.8853902f   // 2*log2(e): tanh(x) = 1 - 2/(1+exp2(x*C2LOG2E))
#define LOG2E 1.4426950f
#define LN2 0.6931472f
#define LOGEPS -18.420681f   // log(1e-8)

#if __has_builtin(__builtin_amdgcn_exp2f)
#define EXP2F(x) __builtin_amdgcn_exp2f(x)
#else
#define EXP2F(x) exp2f(x)
#endif
#if __has_builtin(__builtin_amdgcn_rcpf)
#define RCPF(x) __builtin_amdgcn_rcpf(x)
#else
#define RCPF(x) (1.0f / (x))
#endif
#if __has_builtin(__builtin_amdgcn_logf)
#define LOG2F_(x) __builtin_amdgcn_logf(x)
#else
#define LOG2F_(x) __log2f(x)
#endif

typedef short bf16x8 __attribute__((ext_vector_type(8)));
typedef float f32x4 __attribute__((ext_vector_type(4)));

__device__ __forceinline__ unsigned int f2b_pk(float lo, float hi) {
    union { float f; unsigned int u; } a, b;
    a.f = lo; b.f = hi;
    unsigned int ra = (a.u + 0x7fffu + ((a.u >> 16) & 1u)) >> 16;
    unsigned int rb = (b.u + 0x7fffu + ((b.u >> 16) & 1u)) >> 16;
    return (ra & 0xffffu) | (rb << 16);
}

// ---------------------------------------------------------------------------
// W transpose+convert: Wt[mat][n][k] bf16 from W[mat][k][n] f32
// ---------------------------------------------------------------------------
__global__ __launch_bounds__(256) void wtrans_k(
    const float* __restrict__ W1, const float* __restrict__ W2,
    unsigned short* __restrict__ Wt)
{
    __shared__ float tile[32][33];
    const int mat = blockIdx.z;
    const float* __restrict__ W = mat ? W2 : W1;
    unsigned short* __restrict__ dst = Wt + (size_t)mat * LDIM * DM;
    const int k0 = blockIdx.x * 32, n0 = blockIdx.y * 32;
    const int tx = threadIdx.x & 31, ty = threadIdx.x >> 5;  // 32 x 8
    #pragma unroll
    for (int i = 0; i < 32; i += 8)
        tile[ty + i][tx] = W[(size_t)(k0 + ty + i) * LDIM + n0 + tx];
    __syncthreads();
    #pragma unroll
    for (int i = 0; i < 32; i += 8) {
        union { float f; unsigned int u; } v; v.f = tile[tx][ty + i];
        dst[(size_t)(n0 + ty + i) * DM + k0 + tx] =
            (unsigned short)((v.u + 0x7fffu + ((v.u >> 16) & 1u)) >> 16);
    }
}

// ---------------------------------------------------------------------------
// MFMA GEMM: E[m][l] = exp2(C2LOG2E * (X[m] . W[:,l])), m in [0,4096)
// rows 0..2047 from dec (W1), rows 2048..4095 from enc (W2).
// 64x64 tile, BK=64, 512 threads (8 waves, 4m x 2n), 16x16x32 bf16 MFMA.
// ---------------------------------------------------------------------------
#define APITCH 72  // bf16 elems per LDS row (64 + 8 pad, keeps 16B align)

__global__ __launch_bounds__(512) void gemm_k(
    const float* __restrict__ dec, const float* __restrict__ enc,
    const unsigned short* __restrict__ Wt, float* __restrict__ E)
{
    __shared__ unsigned short As[64 * APITCH];  // [row m][k]
    __shared__ unsigned short Bs[64 * APITCH];  // [row n][k]

    const int tid = threadIdx.x;
    const int m0 = blockIdx.y * 64;
    const int n0 = blockIdx.x * 64;
    const bool is_dec = (m0 < 2048);
    const float* __restrict__ X = is_dec ? dec : enc;
    const unsigned short* __restrict__ Wm = Wt + (is_dec ? 0 : (size_t)LDIM * DM);
    const int xr0 = is_dec ? m0 : m0 - 2048;

    // staging: thread covers row tid>>3, k-chunk (tid&7)*8 elements
    const int arow = tid >> 3;
    const int aoff = (tid & 7) << 3;
    const float* __restrict__ aptr = X + (size_t)(xr0 + arow) * DM + aoff;
    const unsigned short* __restrict__ bptr = Wm + (size_t)(n0 + arow) * DM + aoff;

    const int wave = tid >> 6;
    const int lane = tid & 63;
    const int l15 = lane & 15;
    const int quad = lane >> 4;
    const int wm = wave >> 1;   // 0..3 : m sub-tile (16 rows)
    const int wn = wave & 1;    // 0..1 : n sub-tile (32 cols)

    f32x4 acc[2] = {};
    float4 a0, a1;
    uint4 bb;

    a0 = *(const float4*)(aptr + 0);
    a1 = *(const float4*)(aptr + 4);
    bb = *(const uint4*)(bptr);

    for (int it = 0; it < DM / 64; ++it) {
        if (it) __syncthreads();
        uint4 wa;
        wa.x = f2b_pk(a0.x, a0.y); wa.y = f2b_pk(a0.z, a0.w);
        wa.z = f2b_pk(a1.x, a1.y); wa.w = f2b_pk(a1.z, a1.w);
        *(uint4*)&As[arow * APITCH + aoff] = wa;
        *(uint4*)&Bs[arow * APITCH + aoff] = bb;
        __syncthreads();
        if (it < DM / 64 - 1) {
            const int ko = (it + 1) * 64;
            a0 = *(const float4*)(aptr + ko + 0);
            a1 = *(const float4*)(aptr + ko + 4);
            bb = *(const uint4*)(bptr + ko);
        }
        #pragma unroll
        for (int kb = 0; kb < 64; kb += 32) {
            const bf16x8 af = *(const bf16x8*)&As[(wm * 16 + l15) * APITCH + kb + quad * 8];
            #pragma unroll
            for (int c = 0; c < 2; ++c) {
                const bf16x8 bf = *(const bf16x8*)&Bs[(wn * 32 + c * 16 + l15) * APITCH + kb + quad * 8];
                acc[c] = __builtin_amdgcn_mfma_f32_16x16x32_bf16(af, bf, acc[c], 0, 0, 0);
            }
        }
    }

    // epilogue: E = exp2(C2LOG2E * dot). C/D layout: col=lane&15, row=quad*4+reg
    const int orow = m0 + wm * 16 + quad * 4;
    const int ocol = n0 + wn * 32 + l15;
    #pragma unroll
    for (int c = 0; c < 2; ++c)
        #pragma unroll
        for (int r = 0; r < 4; ++r)
            E[(size_t)(orow + r) * LDIM + ocol + c * 16] = EXP2F(acc[c][r] * C2LOG2E);
}

// ---------------------------------------------------------------------------
// Scores: block = (b, 4 t). 512 threads: s = tid&255, h = tid>>8 splits the
// l-range. score_shifted[t][s] = sum_l vt2[l] / (1 + Ed[t,l]*Ee[s,l]).
// Pair trick: v0/p0 + v1/p1 = (v0*p1 + v1*p0) / (p0*p1) -> 1 rcp per 2 l.
// Mask, log_softmax over s, write out[b, s, t].
// ---------------------------------------------------------------------------
__device__ __forceinline__ void pair_acc(
    const float4 d0, const float4 d1, const float e0, const float e1,
    const float v0, const float v1, float4& acc)
{
    float4 p0, p1, num, den;
    p0.x = fmaf(d0.x, e0, 1.f); p0.y = fmaf(d0.y, e0, 1.f);
    p0.z = fmaf(d0.z, e0, 1.f); p0.w = fmaf(d0.w, e0, 1.f);
    p1.x = fmaf(d1.x, e1, 1.f); p1.y = fmaf(d1.y, e1, 1.f);
    p1.z = fmaf(d1.z, e1, 1.f); p1.w = fmaf(d1.w, e1, 1.f);
    num.x = fmaf(v1, p0.x, v0 * p1.x); num.y = fmaf(v1, p0.y, v0 * p1.y);
    num.z = fmaf(v1, p0.z, v0 * p1.z); num.w = fmaf(v1, p0.w, v0 * p1.w);
    den.x = p0.x * p1.x; den.y = p0.y * p1.y;
    den.z = p0.z * p1.z; den.w = p0.w * p1.w;
    acc.x = fmaf(num.x, RCPF(den.x), acc.x);
    acc.y = fmaf(num.y, RCPF(den.y), acc.y);
    acc.z = fmaf(num.z, RCPF(den.z), acc.z);
    acc.w = fmaf(num.w, RCPF(den.w), acc.w);
}

__global__ __launch_bounds__(512) void scores_k(
    const float* __restrict__ E, const int* __restrict__ lens,
    const float* __restrict__ vt, float* __restrict__ out)
{
    __shared__ __align__(16) float dtr[LDIM][4];   // [l][i]: 4 t-rows, transposed
    __shared__ __align__(16) float vt2s[LDIM];
    __shared__ __align__(16) float4 accs[256];     // half-1 partial sums
    __shared__ float4 wred[4];

    const int tid = threadIdx.x;
    const int s = tid & 255;
    const int h = tid >> 8;
    const int b = blockIdx.y;
    const int t0 = blockIdx.x * 4;
    const float* __restrict__ Ed = E;                        // row = b*TGT + t
    const float* __restrict__ Ee = E + (size_t)2048 * LDIM;  // row = b*SRC + s

    #pragma unroll
    for (int i = h; i < 4; i += 2)
        dtr[s][i] = Ed[(size_t)(b * TGT + t0 + i) * LDIM + s];
    if (tid < 256) vt2s[tid] = -2.0f * vt[tid];
    __syncthreads();

    float4 acc = {0.f, 0.f, 0.f, 0.f};
    const float* __restrict__ erow = Ee + (size_t)(b * SRC + s) * LDIM;

    const int lbase = h * 128;
    for (int l0 = lbase; l0 < lbase + 128; l0 += 4) {
        const float4 e4 = *(const float4*)(erow + l0);
        const float4 v4 = *(const float4*)&vt2s[l0];
        const float4 d0 = *(const float4*)&dtr[l0 + 0][0];
        const float4 d1 = *(const float4*)&dtr[l0 + 1][0];
        const float4 d2 = *(const float4*)&dtr[l0 + 2][0];
        const float4 d3 = *(const float4*)&dtr[l0 + 3][0];
        pair_acc(d0, d1, e4.x, e4.y, v4.x, v4.y, acc);
        pair_acc(d2, d3, e4.z, e4.w, v4.z, v4.w, acc);
    }

    if (h == 1) accs[s] = acc;
    __syncthreads();

    const int wid = tid >> 6, lane = tid & 63;
    float4 mx, sm;

    if (h == 0) {
        const float4 o4 = accs[s];
        acc.x += o4.x; acc.y += o4.y; acc.z += o4.z; acc.w += o4.w;
        const float madd = (s < lens[b]) ? 0.0f : LOGEPS;
        acc.x += madd; acc.y += madd; acc.z += madd; acc.w += madd;

        float4 r = acc;
        #pragma unroll
        for (int off = 32; off > 0; off >>= 1) {
            r.x = fmaxf(r.x, __shfl_down(r.x, off));
            r.y = fmaxf(r.y, __shfl_down(r.y, off));
            r.z = fmaxf(r.z, __shfl_down(r.z, off));
            r.w = fmaxf(r.w, __shfl_down(r.w, off));
        }
        if (lane == 0) wred[wid] = r;
    }
    __syncthreads();

    if (h == 0) {
        mx = wred[0];
        #pragma unroll
        for (int w = 1; w < 4; ++w) {
            mx.x = fmaxf(mx.x, wred[w].x);
            mx.y = fmaxf(mx.y, wred[w].y);
            mx.z = fmaxf(mx.z, wred[w].z);
            mx.w = fmaxf(mx.w, wred[w].w);
        }
    }
    __syncthreads();

    if (h == 0) {
        float4 ex;
        ex.x = EXP2F((acc.x - mx.x) * LOG2E);
        ex.y = EXP2F((acc.y - mx.y) * LOG2E);
        ex.z = EXP2F((acc.z - mx.z) * LOG2E);
        ex.w = EXP2F((acc.w - mx.w) * LOG2E);
        float4 sr = ex;
        #pragma unroll
        for (int off = 32; off > 0; off >>= 1) {
            sr.x += __shfl_down(sr.x, off);
            sr.y += __shfl_down(sr.y, off);
            sr.z += __shfl_down(sr.z, off);
            sr.w += __shfl_down(sr.w, off);
        }
        if (lane == 0) wred[wid] = sr;
    }
    __syncthreads();

    if (h == 0) {
        sm = wred[0];
        #pragma unroll
        for (int w = 1; w < 4; ++w) {
            sm.x += wred[w].x; sm.y += wred[w].y; sm.z += wred[w].z; sm.w += wred[w].w;
        }
        float4 o;
        o.x = acc.x - (mx.x + LOG2F_(sm.x) * LN2);
        o.y = acc.y - (mx.y + LOG2F_(sm.y) * LN2);
        o.z = acc.z - (mx.z + LOG2F_(sm.z) * LN2);
        o.w = acc.w - (mx.w + LOG2F_(sm.w) * LN2);
        *(float4*)(out + (size_t)(b * SRC + s) * TGT + t0) = o;
    }
}

extern "C" void kernel_launch(void* const* d_in, const int* in_sizes, int n_in,
                              void* d_out, int out_size, void* d_ws, size_t ws_size,
                              hipStream_t stream) {
    const float* dec = (const float*)d_in[0];
    const float* enc = (const float*)d_in[1];
    const int* lens  = (const int*)d_in[2];
    const float* W1  = (const float*)d_in[3];
    const float* W2  = (const float*)d_in[4];
    const float* vt  = (const float*)d_in[5];
    float* out = (float*)d_out;

    unsigned short* Wt = (unsigned short*)d_ws;            // 2*256*512 bf16 = 512 KB
    float* E = (float*)((char*)d_ws + (size_t)2 * LDIM * DM * sizeof(unsigned short));
                                                           // 4096*256 f32 = 4 MB

    wtrans_k<<<dim3(16, 8, 2), 256, 0, stream>>>(W1, W2, Wt);
    gemm_k<<<dim3(LDIM / 64, 4096 / 64), 512, 0, stream>>>(dec, enc, Wt, E);
    scores_k<<<dim3(TGT / 4, BATCH), 512, 0, stream>>>(E, lens, vt, out);
}

// Round 4
// 94.586 us; speedup vs baseline: 1.3903x; 1.0374x over previous
//
#include <hip/hip_runtime.h>
#include <hip/hip_bf16.h>

#define TGT 256
#define SRC 256
#define LDIM 256
#define DM 512
#define BATCH 8

#define C2LOG2E 2.8853902f   // 2*log2(e): tanh(x) = 1 - 2/(1+exp2(x*C2LOG2E))
#define LOG2E 1.4426950f
#define LN2 0.6931472f
#define LOGEPS -18.420681f   // log(1e-8)

#if __has_builtin(__builtin_amdgcn_exp2f)
#define EXP2F(x) __builtin_amdgcn_exp2f(x)
#else
#define EXP2F(x) exp2f(x)
#endif
#if __has_builtin(__builtin_amdgcn_rcpf)
#define RCPF(x) __builtin_amdgcn_rcpf(x)
#else
#define RCPF(x) (1.0f / (x))
#endif
#if __has_builtin(__builtin_amdgcn_logf)
#define LOG2F_(x) __builtin_amdgcn_logf(x)
#else
#define LOG2F_(x) __log2f(x)
#endif

typedef short bf16x8 __attribute__((ext_vector_type(8)));
typedef float f32x4 __attribute__((ext_vector_type(4)));

__device__ __forceinline__ unsigned int f2b_pk(float lo, float hi) {
    union { float f; unsigned int u; } a, b;
    a.f = lo; b.f = hi;
    unsigned int ra = (a.u + 0x7fffu + ((a.u >> 16) & 1u)) >> 16;
    unsigned int rb = (b.u + 0x7fffu + ((b.u >> 16) & 1u)) >> 16;
    return (ra & 0xffffu) | (rb << 16);
}

// ---------------------------------------------------------------------------
// W transpose+convert: Wt[mat][n][k] bf16 from W[mat][k][n] f32
// ---------------------------------------------------------------------------
__global__ __launch_bounds__(256) void wtrans_k(
    const float* __restrict__ W1, const float* __restrict__ W2,
    unsigned short* __restrict__ Wt)
{
    __shared__ float tile[32][33];
    const int mat = blockIdx.z;
    const float* __restrict__ W = mat ? W2 : W1;
    unsigned short* __restrict__ dst = Wt + (size_t)mat * LDIM * DM;
    const int k0 = blockIdx.x * 32, n0 = blockIdx.y * 32;
    const int tx = threadIdx.x & 31, ty = threadIdx.x >> 5;  // 32 x 8
    #pragma unroll
    for (int i = 0; i < 32; i += 8)
        tile[ty + i][tx] = W[(size_t)(k0 + ty + i) * LDIM + n0 + tx];
    __syncthreads();
    #pragma unroll
    for (int i = 0; i < 32; i += 8) {
        union { float f; unsigned int u; } v; v.f = tile[tx][ty + i];
        dst[(size_t)(n0 + ty + i) * DM + k0 + tx] =
            (unsigned short)((v.u + 0x7fffu + ((v.u >> 16) & 1u)) >> 16);
    }
}

// ---------------------------------------------------------------------------
// MFMA GEMM: E[m][l] = exp2(C2LOG2E * (X[m] . W[:,l])), m in [0,4096)
// rows 0..2047 from dec (W1), rows 2048..4095 from enc (W2).
// 64x64 tile, BK=128 (4 iters), 512 threads (8 waves, 4m x 2n), 16x16x32 MFMA.
// 1-D grid, bid&7 = batch -> all tiles of batch b on XCD b (E stays in its L2
// for scores_k).
// ---------------------------------------------------------------------------
#define APITCH 136  // bf16 elems per LDS row (128 + 8 pad; row pitch 272B = 16*17, 16B aligned)

__global__ __launch_bounds__(512) void gemm_k(
    const float* __restrict__ dec, const float* __restrict__ enc,
    const unsigned short* __restrict__ Wt, float* __restrict__ E)
{
    __shared__ unsigned short As[64 * APITCH];  // [row m][k]
    __shared__ unsigned short Bs[64 * APITCH];  // [row n][k]

    const int tid = threadIdx.x;
    // bid = (part, n, mt, b): b = XCD id
    const int bid = blockIdx.x;
    const int b    = bid & 7;
    const int j    = bid >> 3;
    const int mt   = j & 3;
    const int n0   = ((j >> 2) & 3) * 64;
    const int part = j >> 4;
    const int m0 = part * 2048 + b * 256 + mt * 64;

    const bool is_dec = (part == 0);
    const float* __restrict__ X = is_dec ? dec : enc;
    const unsigned short* __restrict__ Wm = Wt + (is_dec ? 0 : (size_t)LDIM * DM);
    const int xr0 = b * 256 + mt * 64;

    // staging: thread covers row tid>>3, k-chunk (tid&7)*16 elements
    const int arow = tid >> 3;
    const int aoff = (tid & 7) << 4;
    const float* __restrict__ aptr = X + (size_t)(xr0 + arow) * DM + aoff;
    const unsigned short* __restrict__ bptr = Wm + (size_t)(n0 + arow) * DM + aoff;

    const int wave = tid >> 6;
    const int lane = tid & 63;
    const int l15 = lane & 15;
    const int quad = lane >> 4;
    const int wm = wave >> 1;   // 0..3 : m sub-tile (16 rows)
    const int wn = wave & 1;    // 0..1 : n sub-tile (32 cols)

    f32x4 acc[2] = {};
    float4 a0, a1, a2, a3;
    uint4 bb0, bb1;

    a0 = *(const float4*)(aptr + 0);
    a1 = *(const float4*)(aptr + 4);
    a2 = *(const float4*)(aptr + 8);
    a3 = *(const float4*)(aptr + 12);
    bb0 = *(const uint4*)(bptr + 0);
    bb1 = *(const uint4*)(bptr + 8);

    #pragma unroll
    for (int it = 0; it < DM / 128; ++it) {
        if (it) __syncthreads();
        uint4 wa0, wa1;
        wa0.x = f2b_pk(a0.x, a0.y); wa0.y = f2b_pk(a0.z, a0.w);
        wa0.z = f2b_pk(a1.x, a1.y); wa0.w = f2b_pk(a1.z, a1.w);
        wa1.x = f2b_pk(a2.x, a2.y); wa1.y = f2b_pk(a2.z, a2.w);
        wa1.z = f2b_pk(a3.x, a3.y); wa1.w = f2b_pk(a3.z, a3.w);
        *(uint4*)&As[arow * APITCH + aoff]     = wa0;
        *(uint4*)&As[arow * APITCH + aoff + 8] = wa1;
        *(uint4*)&Bs[arow * APITCH + aoff]     = bb0;
        *(uint4*)&Bs[arow * APITCH + aoff + 8] = bb1;
        __syncthreads();
        if (it < DM / 128 - 1) {
            const int ko = (it + 1) * 128;
            a0 = *(const float4*)(aptr + ko + 0);
            a1 = *(const float4*)(aptr + ko + 4);
            a2 = *(const float4*)(aptr + ko + 8);
            a3 = *(const float4*)(aptr + ko + 12);
            bb0 = *(const uint4*)(bptr + ko + 0);
            bb1 = *(const uint4*)(bptr + ko + 8);
        }
        #pragma unroll
        for (int kb = 0; kb < 128; kb += 32) {
            const bf16x8 af = *(const bf16x8*)&As[(wm * 16 + l15) * APITCH + kb + quad * 8];
            #pragma unroll
            for (int c = 0; c < 2; ++c) {
                const bf16x8 bf = *(const bf16x8*)&Bs[(wn * 32 + c * 16 + l15) * APITCH + kb + quad * 8];
                acc[c] = __builtin_amdgcn_mfma_f32_16x16x32_bf16(af, bf, acc[c], 0, 0, 0);
            }
        }
    }

    // epilogue: E = exp2(C2LOG2E * dot). C/D layout: col=lane&15, row=quad*4+reg
    const int orow = m0 + wm * 16 + quad * 4;
    const int ocol = n0 + wn * 32 + l15;
    #pragma unroll
    for (int c = 0; c < 2; ++c)
        #pragma unroll
        for (int r = 0; r < 4; ++r)
            E[(size_t)(orow + r) * LDIM + ocol + c * 16] = EXP2F(acc[c][r] * C2LOG2E);
}

// ---------------------------------------------------------------------------
// Scores: 1-D grid of 512, b = bid&7 (XCD-pinned), t0 = (bid>>3)*4.
// 512 threads: s = tid&255, h = tid>>8 splits the l-range.
// score_shifted[t][s] = sum_l vt2[l] / (1 + Ed[t,l]*Ee[s,l]).
// Pair trick: v0/p0 + v1/p1 = (v0*p1 + v1*p0) / (p0*p1) -> 1 rcp per 2 l.
// Mask, log_softmax over s, write out[b, s, t].
// ---------------------------------------------------------------------------
__device__ __forceinline__ void pair_acc(
    const float4 d0, const float4 d1, const float e0, const float e1,
    const float v0, const float v1, float4& acc)
{
    float4 p0, p1, num, den;
    p0.x = fmaf(d0.x, e0, 1.f); p0.y = fmaf(d0.y, e0, 1.f);
    p0.z = fmaf(d0.z, e0, 1.f); p0.w = fmaf(d0.w, e0, 1.f);
    p1.x = fmaf(d1.x, e1, 1.f); p1.y = fmaf(d1.y, e1, 1.f);
    p1.z = fmaf(d1.z, e1, 1.f); p1.w = fmaf(d1.w, e1, 1.f);
    num.x = fmaf(v1, p0.x, v0 * p1.x); num.y = fmaf(v1, p0.y, v0 * p1.y);
    num.z = fmaf(v1, p0.z, v0 * p1.z); num.w = fmaf(v1, p0.w, v0 * p1.w);
    den.x = p0.x * p1.x; den.y = p0.y * p1.y;
    den.z = p0.z * p1.z; den.w = p0.w * p1.w;
    acc.x = fmaf(num.x, RCPF(den.x), acc.x);
    acc.y = fmaf(num.y, RCPF(den.y), acc.y);
    acc.z = fmaf(num.z, RCPF(den.z), acc.z);
    acc.w = fmaf(num.w, RCPF(den.w), acc.w);
}

__global__ __launch_bounds__(512) void scores_k(
    const float* __restrict__ E, const int* __restrict__ lens,
    const float* __restrict__ vt, float* __restrict__ out)
{
    __shared__ __align__(16) float dtr[LDIM][4];   // [l][i]: 4 t-rows, transposed
    __shared__ __align__(16) float vt2s[LDIM];
    __shared__ __align__(16) float4 accs[256];     // half-1 partial sums
    __shared__ float4 wred[4];

    const int tid = threadIdx.x;
    const int s = tid & 255;
    const int h = tid >> 8;
    const int b = blockIdx.x & 7;                  // XCD-pinned batch
    const int t0 = (blockIdx.x >> 3) * 4;
    const float* __restrict__ Ed = E;                        // row = b*TGT + t
    const float* __restrict__ Ee = E + (size_t)2048 * LDIM;  // row = b*SRC + s

    #pragma unroll
    for (int i = h; i < 4; i += 2)
        dtr[s][i] = Ed[(size_t)(b * TGT + t0 + i) * LDIM + s];
    if (tid < 256) vt2s[tid] = -2.0f * vt[tid];
    __syncthreads();

    float4 acc = {0.f, 0.f, 0.f, 0.f};
    const float* __restrict__ erow = Ee + (size_t)(b * SRC + s) * LDIM;

    const int lbase = h * 128;
    for (int l0 = lbase; l0 < lbase + 128; l0 += 4) {
        const float4 e4 = *(const float4*)(erow + l0);
        const float4 v4 = *(const float4*)&vt2s[l0];
        const float4 d0 = *(const float4*)&dtr[l0 + 0][0];
        const float4 d1 = *(const float4*)&dtr[l0 + 1][0];
        const float4 d2 = *(const float4*)&dtr[l0 + 2][0];
        const float4 d3 = *(const float4*)&dtr[l0 + 3][0];
        pair_acc(d0, d1, e4.x, e4.y, v4.x, v4.y, acc);
        pair_acc(d2, d3, e4.z, e4.w, v4.z, v4.w, acc);
    }

    if (h == 1) accs[s] = acc;
    __syncthreads();

    const int wid = tid >> 6, lane = tid & 63;
    float4 mx, sm;

    if (h == 0) {
        const float4 o4 = accs[s];
        acc.x += o4.x; acc.y += o4.y; acc.z += o4.z; acc.w += o4.w;
        const float madd = (s < lens[b]) ? 0.0f : LOGEPS;
        acc.x += madd; acc.y += madd; acc.z += madd; acc.w += madd;

        float4 r = acc;
        #pragma unroll
        for (int off = 32; off > 0; off >>= 1) {
            r.x = fmaxf(r.x, __shfl_down(r.x, off));
            r.y = fmaxf(r.y, __shfl_down(r.y, off));
            r.z = fmaxf(r.z, __shfl_down(r.z, off));
            r.w = fmaxf(r.w, __shfl_down(r.w, off));
        }
        if (lane == 0) wred[wid] = r;
    }
    __syncthreads();

    if (h == 0) {
        mx = wred[0];
        #pragma unroll
        for (int w = 1; w < 4; ++w) {
            mx.x = fmaxf(mx.x, wred[w].x);
            mx.y = fmaxf(mx.y, wred[w].y);
            mx.z = fmaxf(mx.z, wred[w].z);
            mx.w = fmaxf(mx.w, wred[w].w);
        }
    }
    __syncthreads();

    if (h == 0) {
        float4 ex;
        ex.x = EXP2F((acc.x - mx.x) * LOG2E);
        ex.y = EXP2F((acc.y - mx.y) * LOG2E);
        ex.z = EXP2F((acc.z - mx.z) * LOG2E);
        ex.w = EXP2F((acc.w - mx.w) * LOG2E);
        float4 sr = ex;
        #pragma unroll
        for (int off = 32; off > 0; off >>= 1) {
            sr.x += __shfl_down(sr.x, off);
            sr.y += __shfl_down(sr.y, off);
            sr.z += __shfl_down(sr.z, off);
            sr.w += __shfl_down(sr.w, off);
        }
        if (lane == 0) wred[wid] = sr;
    }
    __syncthreads();

    if (h == 0) {
        sm = wred[0];
        #pragma unroll
        for (int w = 1; w < 4; ++w) {
            sm.x += wred[w].x; sm.y += wred[w].y; sm.z += wred[w].z; sm.w += wred[w].w;
        }
        float4 o;
        o.x = acc.x - (mx.x + LOG2F_(sm.x) * LN2);
        o.y = acc.y - (mx.y + LOG2F_(sm.y) * LN2);
        o.z = acc.z - (mx.z + LOG2F_(sm.z) * LN2);
        o.w = acc.w - (mx.w + LOG2F_(sm.w) * LN2);
        *(float4*)(out + (size_t)(b * SRC + s) * TGT + t0) = o;
    }
}

extern "C" void kernel_launch(void* const* d_in, const int* in_sizes, int n_in,
                              void* d_out, int out_size, void* d_ws, size_t ws_size,
                              hipStream_t stream) {
    const float* dec = (const float*)d_in[0];
    const float* enc = (const float*)d_in[1];
    const int* lens  = (const int*)d_in[2];
    const float* W1  = (const float*)d_in[3];
    const float* W2  = (const float*)d_in[4];
    const float* vt  = (const float*)d_in[5];
    float* out = (float*)d_out;

    unsigned short* Wt = (unsigned short*)d_ws;            // 2*256*512 bf16 = 512 KB
    float* E = (float*)((char*)d_ws + (size_t)2 * LDIM * DM * sizeof(unsigned short));
                                                           // 4096*256 f32 = 4 MB

    wtrans_k<<<dim3(16, 8, 2), 256, 0, stream>>>(W1, W2, Wt);
    gemm_k<<<256, 512, 0, stream>>>(dec, enc, Wt, E);
    scores_k<<<512, 512, 0, stream>>>(E, lens, vt, out);
}